// Round 8
// baseline (1295.969 us; speedup 1.0000x reference)
//
#include <hip/hip_runtime.h>

// GAT: N=100000 E=1600000 NFEAT=256 NHID=64 NHEADS=4 NCLASS=40 (hardcoded dims).
// Inputs f32 (proved r1). OUTPUT IS FLOAT32 (r7 post-mortem: reference returns f32;
// 7 rounds of ushort writes filled only half the f32 out buffer -> invariant 4.5).
// CSR-by-dst pipeline. Intermediates f32 (~232MB ws) or bf16 Wh1/x (~129MB) by ws_size;
// sentinel -2.0 (absmax 2.5) if neither fits.

#define ALPHA 0.2f
constexpr int N_ = 100000;
constexpr int E_ = 1600000;
constexpr long OUTEL = (long)N_ * 40;

__device__ __forceinline__ float bf2f(unsigned short u) {
    return __uint_as_float(((unsigned)u) << 16);
}
__device__ __forceinline__ unsigned short f2bf(float f) {
    unsigned u = __float_as_uint(f);
    u += 0x7fffu + ((u >> 16) & 1u);   // RNE
    return (unsigned short)(u >> 16);
}
__device__ __forceinline__ float ldg_(const float* p, size_t i) { return p[i]; }
__device__ __forceinline__ float ldg_(const unsigned short* p, size_t i) { return bf2f(p[i]); }
__device__ __forceinline__ void stg_(float* p, size_t i, float v) { p[i] = v; }
__device__ __forceinline__ void stg_(unsigned short* p, size_t i, float v) { p[i] = f2bf(v); }

__global__ void k_sent(float* out, long n, float v) {
    long i = blockIdx.x * 256L + threadIdx.x;
    if (i < n) out[i] = v;
}

// ---------------- CSR build ----------------

__global__ void k_zero(int* p, int n) {
    int i = blockIdx.x * 256 + threadIdx.x;
    if (i < n) p[i] = 0;
}

__global__ void k_count(const int* __restrict__ dst, int* __restrict__ deg) {
    int e = blockIdx.x * 256 + threadIdx.x;
    if (e < E_) {
        int d = dst[e];
        if ((unsigned)d < (unsigned)N_) atomicAdd(&deg[d], 1);
    }
}

__global__ void k_partial(const int* __restrict__ deg, int* __restrict__ part) {
    __shared__ int sd[256];
    int b = blockIdx.x, t = threadIdx.x;
    int base = b * 1024;
    int s = 0;
    for (int i = 0; i < 4; i++) {
        int idx = base + t * 4 + i;
        if (idx < N_) s += deg[idx];
    }
    sd[t] = s;
    __syncthreads();
    for (int o = 128; o; o >>= 1) {
        if (t < o) sd[t] += sd[t + o];
        __syncthreads();
    }
    if (t == 0) part[b] = sd[0];
}

__global__ void k_scan_part(int* part, int nchunks, int* rowptr) {
    if (threadIdx.x == 0 && blockIdx.x == 0) {
        int run = 0;
        for (int b = 0; b < nchunks; b++) {
            int v = part[b];
            part[b] = run;
            run += v;
        }
        rowptr[N_] = run;
    }
}

__global__ void k_scan_final(const int* __restrict__ deg, const int* __restrict__ part,
                             int* __restrict__ rowptr, int* __restrict__ cursor) {
    __shared__ int sd[256];
    int b = blockIdx.x, t = threadIdx.x;
    int base = b * 1024;
    int v[4];
    int s = 0;
    for (int i = 0; i < 4; i++) {
        int idx = base + t * 4 + i;
        v[i] = (idx < N_) ? deg[idx] : 0;
        s += v[i];
    }
    sd[t] = s;
    __syncthreads();
    for (int o = 1; o < 256; o <<= 1) {
        int add = (t >= o) ? sd[t - o] : 0;
        __syncthreads();
        sd[t] += add;
        __syncthreads();
    }
    int off0 = part[b] + (sd[t] - s);
    for (int i = 0; i < 4; i++) {
        int idx = base + t * 4 + i;
        if (idx < N_) {
            rowptr[idx] = off0;
            cursor[idx] = off0;
            off0 += v[i];
        }
    }
}

__global__ void k_fill(const int* __restrict__ src, const int* __restrict__ dst,
                       int* __restrict__ cursor, int* __restrict__ csr) {
    int e = blockIdx.x * 256 + threadIdx.x;
    if (e < E_) {
        int d = dst[e];
        if ((unsigned)d < (unsigned)N_) {
            int p = atomicAdd(&cursor[d], 1);
            if ((unsigned)p < (unsigned)E_) csr[p] = src[e];
        }
    }
}

// ---------------- GEMM1: Wh1[n][head*64+f] = h @ W_heads[head] ----------------

template <typename T>
__global__ __launch_bounds__(256) void k_gemm1(const float* __restrict__ h,
                                               const float* __restrict__ Whd,
                                               T* __restrict__ Wh1) {
    __shared__ float AsT[32][68];
    __shared__ float Bs[32][64];
    int row0 = blockIdx.x * 64;
    int head = blockIdx.y;
    const float* B = Whd + head * 16384;
    int t = threadIdx.x;
    int tr = (t >> 4) << 2;
    int tc = (t & 15) << 2;
    float acc[4][4] = {};

    for (int k0 = 0; k0 < 256; k0 += 32) {
#pragma unroll
        for (int u = 0; u < 2; u++) {
            int j = u * 256 + t;
            int r = j >> 3;
            int q = (j & 7) << 2;
            int gr = row0 + r;
            float4 v = make_float4(0.f, 0.f, 0.f, 0.f);
            if (gr < N_) v = *(const float4*)(h + (size_t)gr * 256 + k0 + q);
            AsT[q][r] = v.x; AsT[q + 1][r] = v.y; AsT[q + 2][r] = v.z; AsT[q + 3][r] = v.w;
        }
#pragma unroll
        for (int u = 0; u < 2; u++) {
            int j = u * 256 + t;
            int r = j >> 4;
            int q = (j & 15) << 2;
            *(float4*)(&Bs[r][q]) = *(const float4*)(B + (size_t)(k0 + r) * 64 + q);
        }
        __syncthreads();
#pragma unroll
        for (int kk = 0; kk < 32; kk++) {
            float4 av = *(const float4*)(&AsT[kk][tr]);
            float4 bv = *(const float4*)(&Bs[kk][tc]);
            acc[0][0] += av.x * bv.x; acc[0][1] += av.x * bv.y; acc[0][2] += av.x * bv.z; acc[0][3] += av.x * bv.w;
            acc[1][0] += av.y * bv.x; acc[1][1] += av.y * bv.y; acc[1][2] += av.y * bv.z; acc[1][3] += av.y * bv.w;
            acc[2][0] += av.z * bv.x; acc[2][1] += av.z * bv.y; acc[2][2] += av.z * bv.z; acc[2][3] += av.z * bv.w;
            acc[3][0] += av.w * bv.x; acc[3][1] += av.w * bv.y; acc[3][2] += av.w * bv.z; acc[3][3] += av.w * bv.w;
        }
        __syncthreads();
    }
#pragma unroll
    for (int i = 0; i < 4; i++) {
        int gr = row0 + tr + i;
        if (gr < N_) {
#pragma unroll
            for (int q = 0; q < 4; q++)
                stg_(Wh1, (size_t)gr * 256 + head * 64 + tc + q, acc[i][q]);
        }
    }
}

// ---------------- s1 ----------------

template <typename T>
__global__ __launch_bounds__(256) void k_s1(const T* __restrict__ Wh1,
                                            const float* __restrict__ ah,
                                            float* __restrict__ s1s, float* __restrict__ s1d) {
    int n = blockIdx.x;
    int w = threadIdx.x >> 6, lane = threadIdx.x & 63;
    float wv = ldg_(Wh1, (size_t)n * 256 + w * 64 + lane);
    float r1 = wv * ah[w * 128 + lane];
    float r2 = wv * ah[w * 128 + 64 + lane];
    for (int o = 32; o; o >>= 1) {
        r1 += __shfl_xor(r1, o);
        r2 += __shfl_xor(r2, o);
    }
    if (lane == 0) {
        s1s[n * 4 + w] = r1;
        s1d[n * 4 + w] = r2;
    }
}

// ---------------- layer-1 aggregate ----------------

template <typename TW, typename TX>
__global__ __launch_bounds__(256) void k_agg1(const int* __restrict__ rowptr, const int* __restrict__ csr,
                                              const float* __restrict__ s1s, const float* __restrict__ s1d,
                                              const TW* __restrict__ Wh1, TX* __restrict__ x) {
    int n = blockIdx.x;
    int base = rowptr[n], deg = rowptr[n + 1] - base;
    if (deg < 0) deg = 0;
    int w = threadIdx.x >> 6, lane = threadIdx.x & 63;
    float sdw = s1d[n * 4 + w];

    float mx = -INFINITY;
    for (int i = lane; i < deg; i += 64) {
        int s = csr[base + i];
        if ((unsigned)s >= (unsigned)N_) s = 0;
        float e = s1s[s * 4 + w] + sdw;
        e = e > 0.f ? e : ALPHA * e;
        mx = fmaxf(mx, e);
    }
    for (int o = 32; o; o >>= 1) mx = fmaxf(mx, __shfl_xor(mx, o));
    float sm = 0.f;
    for (int i = lane; i < deg; i += 64) {
        int s = csr[base + i];
        if ((unsigned)s >= (unsigned)N_) s = 0;
        float e = s1s[s * 4 + w] + sdw;
        e = e > 0.f ? e : ALPHA * e;
        sm += expf(e - mx);
    }
    for (int o = 32; o; o >>= 1) sm += __shfl_xor(sm, o);

    float invd = (deg > 0) ? 1.f / sm : 0.f;
    float acc = 0.f;
    for (int i = 0; i < deg; i++) {
        int s = csr[base + i];
        if ((unsigned)s >= (unsigned)N_) s = 0;
        float e = s1s[s * 4 + w] + sdw;
        e = e > 0.f ? e : ALPHA * e;
        float att = expf(e - mx) * invd;
        acc += att * ldg_(Wh1, (size_t)s * 256 + threadIdx.x);
    }
    float r = acc > 0.f ? acc : (expf(acc) - 1.f);   // elu
    stg_(x, (size_t)n * 256 + threadIdx.x, r);
}

// ---------------- GEMM2 (+fused s2) ----------------

template <typename TX>
__global__ __launch_bounds__(256) void k_gemm2(const TX* __restrict__ x,
                                               const float* __restrict__ Wo,
                                               const float* __restrict__ ao,
                                               float* __restrict__ Wh2,
                                               float* __restrict__ s2s, float* __restrict__ s2d) {
    __shared__ float Wf[256 * 40];
    __shared__ float xs[4][256];
    int t = threadIdx.x;
#pragma unroll
    for (int i = 0; i < 40; i++) {
        int idx = i * 256 + t;
        Wf[idx] = Wo[idx];
    }
    int w = t >> 6, lane = t & 63;
    int n = blockIdx.x * 4 + w;
    if (n < N_) {
#pragma unroll
        for (int q = 0; q < 4; q++)
            xs[w][lane * 4 + q] = ldg_(x, (size_t)n * 256 + lane * 4 + q);
    }
    __syncthreads();
    if (n < N_) {
        int c = lane;
        float acc = 0.f;
        if (c < 40) {
            for (int k = 0; k < 256; k += 4) {
                float4 xk = *(const float4*)(&xs[w][k]);
                acc += xk.x * Wf[k * 40 + c] + xk.y * Wf[(k + 1) * 40 + c] +
                       xk.z * Wf[(k + 2) * 40 + c] + xk.w * Wf[(k + 3) * 40 + c];
            }
            Wh2[(size_t)n * 40 + c] = acc;
        }
        float a1 = (c < 40) ? ao[c] : 0.f;
        float a2 = (c < 40) ? ao[40 + c] : 0.f;
        float r1 = acc * a1, r2 = acc * a2;
        for (int o = 32; o; o >>= 1) {
            r1 += __shfl_xor(r1, o);
            r2 += __shfl_xor(r2, o);
        }
        if (lane == 0) {
            s2s[n] = r1;
            s2d[n] = r2;
        }
    }
}

// ---------------- layer-2 aggregate + log_softmax (FLOAT32 out) ----------------

__global__ __launch_bounds__(64) void k_agg2(const int* __restrict__ rowptr, const int* __restrict__ csr,
                                             const float* __restrict__ s2s, const float* __restrict__ s2d,
                                             const float* __restrict__ Wh2,
                                             float* __restrict__ out) {
    int n = blockIdx.x;
    int base = rowptr[n], deg = rowptr[n + 1] - base;
    if (deg < 0) deg = 0;
    int lane = threadIdx.x;
    float sdw = s2d[n];

    float mx = -INFINITY;
    for (int i = lane; i < deg; i += 64) {
        int s = csr[base + i];
        if ((unsigned)s >= (unsigned)N_) s = 0;
        float e = s2s[s] + sdw;
        e = e > 0.f ? e : ALPHA * e;
        mx = fmaxf(mx, e);
    }
    for (int o = 32; o; o >>= 1) mx = fmaxf(mx, __shfl_xor(mx, o));
    float sm = 0.f;
    for (int i = lane; i < deg; i += 64) {
        int s = csr[base + i];
        if ((unsigned)s >= (unsigned)N_) s = 0;
        float e = s2s[s] + sdw;
        e = e > 0.f ? e : ALPHA * e;
        sm += expf(e - mx);
    }
    for (int o = 32; o; o >>= 1) sm += __shfl_xor(sm, o);
    float invd = (deg > 0) ? 1.f / sm : 0.f;

    float acc = 0.f;
    for (int i = 0; i < deg; i++) {
        int s = csr[base + i];
        if ((unsigned)s >= (unsigned)N_) s = 0;
        float e = s2s[s] + sdw;
        e = e > 0.f ? e : ALPHA * e;
        float att = expf(e - mx) * invd;
        if (lane < 40) acc += att * Wh2[(size_t)s * 40 + lane];
    }

    float v = (lane < 40) ? acc : -INFINITY;
    float mv = v;
    for (int o = 32; o; o >>= 1) mv = fmaxf(mv, __shfl_xor(mv, o));
    float ex = (lane < 40) ? expf(acc - mv) : 0.f;
    float se = ex;
    for (int o = 32; o; o >>= 1) se += __shfl_xor(se, o);
    if (lane < 40) out[(size_t)n * 40 + lane] = acc - mv - logf(se);
}

// ---------------- host ----------------

extern "C" void kernel_launch(void* const* d_in, const int* in_sizes, int n_in,
                              void* d_out, int out_size, void* d_ws, size_t ws_size,
                              hipStream_t stream) {
    const float* h   = (const float*)d_in[0];
    const int*   ei  = (const int*)d_in[1];
    const float* Whd = (const float*)d_in[2];
    const float* ah  = (const float*)d_in[3];
    const float* Wo  = (const float*)d_in[4];
    const float* ao  = (const float*)d_in[5];
    float* out = (float*)d_out;   // reference output dtype is FLOAT32

    const int* src = ei;
    const int* dst = ei + E_;
    const int nchunks = (N_ + 1023) / 1024;   // 98

    char* ws = (char*)d_ws;
    size_t off = 0;
    auto alloc = [&](size_t bytes) -> char* {
        size_t a = (off + 255) & ~(size_t)255;
        off = a + bytes;
        return ws + a;
    };
    int* rowptr = (int*)alloc((size_t)(N_ + 1) * 4);
    int* cursor = (int*)alloc((size_t)N_ * 4);
    int* deg    = (int*)alloc((size_t)N_ * 4);
    int* part   = (int*)alloc((size_t)(nchunks + 1) * 4);
    int* csr    = (int*)alloc((size_t)E_ * 4);
    float* s1s  = (float*)alloc((size_t)N_ * 4 * 4);
    float* s1d  = (float*)alloc((size_t)N_ * 4 * 4);
    float* Wh2  = (float*)alloc((size_t)N_ * 40 * 4);
    float* s2s  = (float*)alloc((size_t)N_ * 4);
    float* s2d  = (float*)alloc((size_t)N_ * 4);
    size_t base_need = off;
    size_t need_f32  = base_need + 2 * ((size_t)N_ * 256 * 4 + 256);
    size_t need_bf16 = base_need + 2 * ((size_t)N_ * 256 * 2 + 256);

    bool use_f32;
    if (ws_size >= need_f32) use_f32 = true;
    else if (ws_size >= need_bf16) use_f32 = false;
    else {
        k_sent<<<(int)((OUTEL + 255) / 256), 256, 0, stream>>>(out, OUTEL, -2.0f);
        return;
    }

    // CSR build
    k_zero<<<(N_ + 255) / 256, 256, 0, stream>>>(deg, N_);
    k_count<<<(E_ + 255) / 256, 256, 0, stream>>>(dst, deg);
    k_partial<<<nchunks, 256, 0, stream>>>(deg, part);
    k_scan_part<<<1, 64, 0, stream>>>(part, nchunks, rowptr);
    k_scan_final<<<nchunks, 256, 0, stream>>>(deg, part, rowptr, cursor);
    k_fill<<<(E_ + 255) / 256, 256, 0, stream>>>(src, dst, cursor, csr);

    dim3 g1((N_ + 63) / 64, 4);
    if (use_f32) {
        float* Wh1 = (float*)alloc((size_t)N_ * 256 * 4);
        float* x   = (float*)alloc((size_t)N_ * 256 * 4);
        k_gemm1<float><<<g1, 256, 0, stream>>>(h, Whd, Wh1);
        k_s1<float><<<N_, 256, 0, stream>>>(Wh1, ah, s1s, s1d);
        k_agg1<float, float><<<N_, 256, 0, stream>>>(rowptr, csr, s1s, s1d, Wh1, x);
        k_gemm2<float><<<(N_ + 3) / 4, 256, 0, stream>>>(x, Wo, ao, Wh2, s2s, s2d);
    } else {
        unsigned short* Wh1 = (unsigned short*)alloc((size_t)N_ * 256 * 2);
        unsigned short* x   = (unsigned short*)alloc((size_t)N_ * 256 * 2);
        k_gemm1<unsigned short><<<g1, 256, 0, stream>>>(h, Whd, Wh1);
        k_s1<unsigned short><<<N_, 256, 0, stream>>>(Wh1, ah, s1s, s1d);
        k_agg1<unsigned short, unsigned short><<<N_, 256, 0, stream>>>(rowptr, csr, s1s, s1d, Wh1, x);
        k_gemm2<unsigned short><<<(N_ + 3) / 4, 256, 0, stream>>>(x, Wo, ao, Wh2, s2s, s2d);
    }
    k_agg2<<<N_, 64, 0, stream>>>(rowptr, csr, s2s, s2d, Wh2, out);
}

// Round 9
// 1233.469 us; speedup vs baseline: 1.0507x; 1.0507x over previous
//
#include <hip/hip_runtime.h>

// GAT: N=100000 E=1600000 NFEAT=256 NHID=64 NHEADS=4 NCLASS=40 (hardcoded dims).
// Inputs f32, OUTPUT f32. r8 passed (absmax 0.0156, 1296us); k_agg1 was 473us
// VALU-bound (256 threads redundantly recomputing expf per edge).
// r9: precompute att per (edge,head) once (k_att1/k_att2), aggregation becomes
// pure gather-FMA (k_agg1v/k_agg2v). Wh1 f32; x f32 (tier A ~264MB) or bf16
// fallback (tier B ~213MB); sentinel -2.0 if neither fits.

#define ALPHA 0.2f
constexpr int N_ = 100000;
constexpr int E_ = 1600000;
constexpr long OUTEL = (long)N_ * 40;

__device__ __forceinline__ float bf2f(unsigned short u) {
    return __uint_as_float(((unsigned)u) << 16);
}
__device__ __forceinline__ unsigned short f2bf(float f) {
    unsigned u = __float_as_uint(f);
    u += 0x7fffu + ((u >> 16) & 1u);   // RNE
    return (unsigned short)(u >> 16);
}
__device__ __forceinline__ float ldg_(const float* p, size_t i) { return p[i]; }
__device__ __forceinline__ float ldg_(const unsigned short* p, size_t i) { return bf2f(p[i]); }
__device__ __forceinline__ void stg_(float* p, size_t i, float v) { p[i] = v; }
__device__ __forceinline__ void stg_(unsigned short* p, size_t i, float v) { p[i] = f2bf(v); }

__global__ void k_sent(float* out, long n, float v) {
    long i = blockIdx.x * 256L + threadIdx.x;
    if (i < n) out[i] = v;
}

// ---------------- CSR build ----------------

__global__ void k_zero(int* p, int n) {
    int i = blockIdx.x * 256 + threadIdx.x;
    if (i < n) p[i] = 0;
}

__global__ void k_count(const int* __restrict__ dst, int* __restrict__ deg) {
    int e = blockIdx.x * 256 + threadIdx.x;
    if (e < E_) {
        int d = dst[e];
        if ((unsigned)d < (unsigned)N_) atomicAdd(&deg[d], 1);
    }
}

__global__ void k_partial(const int* __restrict__ deg, int* __restrict__ part) {
    __shared__ int sd[256];
    int b = blockIdx.x, t = threadIdx.x;
    int base = b * 1024;
    int s = 0;
    for (int i = 0; i < 4; i++) {
        int idx = base + t * 4 + i;
        if (idx < N_) s += deg[idx];
    }
    sd[t] = s;
    __syncthreads();
    for (int o = 128; o; o >>= 1) {
        if (t < o) sd[t] += sd[t + o];
        __syncthreads();
    }
    if (t == 0) part[b] = sd[0];
}

__global__ void k_scan_part(int* part, int nchunks, int* rowptr) {
    if (threadIdx.x == 0 && blockIdx.x == 0) {
        int run = 0;
        for (int b = 0; b < nchunks; b++) {
            int v = part[b];
            part[b] = run;
            run += v;
        }
        rowptr[N_] = run;
    }
}

__global__ void k_scan_final(const int* __restrict__ deg, const int* __restrict__ part,
                             int* __restrict__ rowptr, int* __restrict__ cursor) {
    __shared__ int sd[256];
    int b = blockIdx.x, t = threadIdx.x;
    int base = b * 1024;
    int v[4];
    int s = 0;
    for (int i = 0; i < 4; i++) {
        int idx = base + t * 4 + i;
        v[i] = (idx < N_) ? deg[idx] : 0;
        s += v[i];
    }
    sd[t] = s;
    __syncthreads();
    for (int o = 1; o < 256; o <<= 1) {
        int add = (t >= o) ? sd[t - o] : 0;
        __syncthreads();
        sd[t] += add;
        __syncthreads();
    }
    int off0 = part[b] + (sd[t] - s);
    for (int i = 0; i < 4; i++) {
        int idx = base + t * 4 + i;
        if (idx < N_) {
            rowptr[idx] = off0;
            cursor[idx] = off0;
            off0 += v[i];
        }
    }
}

__global__ void k_fill(const int* __restrict__ src, const int* __restrict__ dst,
                       int* __restrict__ cursor, int* __restrict__ csr) {
    int e = blockIdx.x * 256 + threadIdx.x;
    if (e < E_) {
        int d = dst[e];
        if ((unsigned)d < (unsigned)N_) {
            int p = atomicAdd(&cursor[d], 1);
            if ((unsigned)p < (unsigned)E_) csr[p] = src[e];
        }
    }
}

// ---------------- GEMM1: Wh1[n][head*64+f] = h @ W_heads[head] (f32) ----------------

__global__ __launch_bounds__(256) void k_gemm1(const float* __restrict__ h,
                                               const float* __restrict__ Whd,
                                               float* __restrict__ Wh1) {
    __shared__ float AsT[32][68];
    __shared__ float Bs[32][64];
    int row0 = blockIdx.x * 64;
    int head = blockIdx.y;
    const float* B = Whd + head * 16384;
    int t = threadIdx.x;
    int tr = (t >> 4) << 2;
    int tc = (t & 15) << 2;
    float acc[4][4] = {};

    for (int k0 = 0; k0 < 256; k0 += 32) {
#pragma unroll
        for (int u = 0; u < 2; u++) {
            int j = u * 256 + t;
            int r = j >> 3;
            int q = (j & 7) << 2;
            int gr = row0 + r;
            float4 v = make_float4(0.f, 0.f, 0.f, 0.f);
            if (gr < N_) v = *(const float4*)(h + (size_t)gr * 256 + k0 + q);
            AsT[q][r] = v.x; AsT[q + 1][r] = v.y; AsT[q + 2][r] = v.z; AsT[q + 3][r] = v.w;
        }
#pragma unroll
        for (int u = 0; u < 2; u++) {
            int j = u * 256 + t;
            int r = j >> 4;
            int q = (j & 15) << 2;
            *(float4*)(&Bs[r][q]) = *(const float4*)(B + (size_t)(k0 + r) * 64 + q);
        }
        __syncthreads();
#pragma unroll
        for (int kk = 0; kk < 32; kk++) {
            float4 av = *(const float4*)(&AsT[kk][tr]);
            float4 bv = *(const float4*)(&Bs[kk][tc]);
            acc[0][0] += av.x * bv.x; acc[0][1] += av.x * bv.y; acc[0][2] += av.x * bv.z; acc[0][3] += av.x * bv.w;
            acc[1][0] += av.y * bv.x; acc[1][1] += av.y * bv.y; acc[1][2] += av.y * bv.z; acc[1][3] += av.y * bv.w;
            acc[2][0] += av.z * bv.x; acc[2][1] += av.z * bv.y; acc[2][2] += av.z * bv.z; acc[2][3] += av.z * bv.w;
            acc[3][0] += av.w * bv.x; acc[3][1] += av.w * bv.y; acc[3][2] += av.w * bv.z; acc[3][3] += av.w * bv.w;
        }
        __syncthreads();
    }
#pragma unroll
    for (int i = 0; i < 4; i++) {
        int gr = row0 + tr + i;
        if (gr < N_) {
            float4 o = make_float4(acc[i][0], acc[i][1], acc[i][2], acc[i][3]);
            *(float4*)(Wh1 + (size_t)gr * 256 + head * 64 + tc) = o;
        }
    }
}

// ---------------- s1 ----------------

__global__ __launch_bounds__(256) void k_s1(const float* __restrict__ Wh1,
                                            const float* __restrict__ ah,
                                            float* __restrict__ s1s, float* __restrict__ s1d) {
    int n = blockIdx.x;
    int w = threadIdx.x >> 6, lane = threadIdx.x & 63;
    float wv = Wh1[(size_t)n * 256 + w * 64 + lane];
    float r1 = wv * ah[w * 128 + lane];
    float r2 = wv * ah[w * 128 + 64 + lane];
    for (int o = 32; o; o >>= 1) {
        r1 += __shfl_xor(r1, o);
        r2 += __shfl_xor(r2, o);
    }
    if (lane == 0) {
        s1s[n * 4 + w] = r1;
        s1d[n * 4 + w] = r2;
    }
}

// ---------------- att1: per-node softmax -> att per (csr_pos, head) ----------------

__global__ __launch_bounds__(256) void k_att1(const int* __restrict__ rowptr, const int* __restrict__ csr,
                                              const float* __restrict__ s1s, const float* __restrict__ s1d,
                                              float* __restrict__ att1) {
    int n = blockIdx.x;
    int base = rowptr[n], deg = rowptr[n + 1] - base;
    if (deg < 0) deg = 0;
    int t = threadIdx.x;
    int w = t >> 6, lane = t & 63;
    float sdw = s1d[n * 4 + w];
    __shared__ float smx[4], sinv[4];

    float mx = -INFINITY;
    for (int i = lane; i < deg; i += 64) {
        int s = csr[base + i];
        if ((unsigned)s >= (unsigned)N_) s = 0;
        float e = s1s[s * 4 + w] + sdw;
        e = e > 0.f ? e : ALPHA * e;
        mx = fmaxf(mx, e);
    }
    for (int o = 32; o; o >>= 1) mx = fmaxf(mx, __shfl_xor(mx, o));
    float sm = 0.f;
    for (int i = lane; i < deg; i += 64) {
        int s = csr[base + i];
        if ((unsigned)s >= (unsigned)N_) s = 0;
        float e = s1s[s * 4 + w] + sdw;
        e = e > 0.f ? e : ALPHA * e;
        sm += expf(e - mx);
    }
    for (int o = 32; o; o >>= 1) sm += __shfl_xor(sm, o);
    if (lane == 0) {
        smx[w] = mx;
        sinv[w] = (deg > 0) ? 1.f / sm : 0.f;
    }
    __syncthreads();

    int m4 = deg * 4;
    for (int idx = t; idx < m4; idx += 256) {
        int i = idx >> 2, ww = idx & 3;
        int s = csr[base + i];
        if ((unsigned)s >= (unsigned)N_) s = 0;
        float e = s1s[s * 4 + ww] + s1d[n * 4 + ww];
        e = e > 0.f ? e : ALPHA * e;
        att1[(size_t)(base + i) * 4 + ww] = expf(e - smx[ww]) * sinv[ww];
    }
}

// ---------------- layer-1 aggregate: pure gather-FMA (128 thr x 2 feats) ----------------

template <typename TX>
__global__ __launch_bounds__(128) void k_agg1v(const int* __restrict__ rowptr, const int* __restrict__ csr,
                                               const float* __restrict__ att1,
                                               const float* __restrict__ Wh1, TX* __restrict__ x) {
    int n = blockIdx.x;
    int base = rowptr[n], deg = rowptr[n + 1] - base;
    if (deg < 0) deg = 0;
    int t = threadIdx.x;
    int f = t * 2;
    int w = f >> 6;
    float a0 = 0.f, a1 = 0.f;
    int i = 0;
    for (; i + 1 < deg; i += 2) {
        int s0 = csr[base + i], s1 = csr[base + i + 1];
        float at0 = att1[(size_t)(base + i) * 4 + w];
        float at1 = att1[(size_t)(base + i + 1) * 4 + w];
        if ((unsigned)s0 >= (unsigned)N_) s0 = 0;
        if ((unsigned)s1 >= (unsigned)N_) s1 = 0;
        float2 v0 = *(const float2*)(Wh1 + (size_t)s0 * 256 + f);
        float2 v1 = *(const float2*)(Wh1 + (size_t)s1 * 256 + f);
        a0 += at0 * v0.x + at1 * v1.x;
        a1 += at0 * v0.y + at1 * v1.y;
    }
    if (i < deg) {
        int s0 = csr[base + i];
        float at0 = att1[(size_t)(base + i) * 4 + w];
        if ((unsigned)s0 >= (unsigned)N_) s0 = 0;
        float2 v0 = *(const float2*)(Wh1 + (size_t)s0 * 256 + f);
        a0 += at0 * v0.x;
        a1 += at0 * v0.y;
    }
    a0 = a0 > 0.f ? a0 : (expf(a0) - 1.f);   // elu
    a1 = a1 > 0.f ? a1 : (expf(a1) - 1.f);
    stg_(x, (size_t)n * 256 + f, a0);
    stg_(x, (size_t)n * 256 + f + 1, a1);
}

// ---------------- GEMM2 (+fused s2) ----------------

template <typename TX>
__global__ __launch_bounds__(256) void k_gemm2(const TX* __restrict__ x,
                                               const float* __restrict__ Wo,
                                               const float* __restrict__ ao,
                                               float* __restrict__ Wh2,
                                               float* __restrict__ s2s, float* __restrict__ s2d) {
    __shared__ float Wf[256 * 40];
    __shared__ float xs[4][256];
    int t = threadIdx.x;
#pragma unroll
    for (int i = 0; i < 40; i++) {
        int idx = i * 256 + t;
        Wf[idx] = Wo[idx];
    }
    int w = t >> 6, lane = t & 63;
    int n = blockIdx.x * 4 + w;
    if (n < N_) {
#pragma unroll
        for (int q = 0; q < 4; q++)
            xs[w][lane * 4 + q] = ldg_(x, (size_t)n * 256 + lane * 4 + q);
    }
    __syncthreads();
    if (n < N_) {
        int c = lane;
        float acc = 0.f;
        if (c < 40) {
            for (int k = 0; k < 256; k += 4) {
                float4 xk = *(const float4*)(&xs[w][k]);
                acc += xk.x * Wf[k * 40 + c] + xk.y * Wf[(k + 1) * 40 + c] +
                       xk.z * Wf[(k + 2) * 40 + c] + xk.w * Wf[(k + 3) * 40 + c];
            }
            Wh2[(size_t)n * 40 + c] = acc;
        }
        float a1 = (c < 40) ? ao[c] : 0.f;
        float a2 = (c < 40) ? ao[40 + c] : 0.f;
        float r1 = acc * a1, r2 = acc * a2;
        for (int o = 32; o; o >>= 1) {
            r1 += __shfl_xor(r1, o);
            r2 += __shfl_xor(r2, o);
        }
        if (lane == 0) {
            s2s[n] = r1;
            s2d[n] = r2;
        }
    }
}

// ---------------- att2 ----------------

__global__ __launch_bounds__(64) void k_att2(const int* __restrict__ rowptr, const int* __restrict__ csr,
                                             const float* __restrict__ s2s, const float* __restrict__ s2d,
                                             float* __restrict__ att2) {
    int n = blockIdx.x;
    int base = rowptr[n], deg = rowptr[n + 1] - base;
    if (deg < 0) deg = 0;
    int lane = threadIdx.x;
    float sdw = s2d[n];

    float mx = -INFINITY;
    for (int i = lane; i < deg; i += 64) {
        int s = csr[base + i];
        if ((unsigned)s >= (unsigned)N_) s = 0;
        float e = s2s[s] + sdw;
        e = e > 0.f ? e : ALPHA * e;
        mx = fmaxf(mx, e);
    }
    for (int o = 32; o; o >>= 1) mx = fmaxf(mx, __shfl_xor(mx, o));
    float sm = 0.f;
    for (int i = lane; i < deg; i += 64) {
        int s = csr[base + i];
        if ((unsigned)s >= (unsigned)N_) s = 0;
        float e = s2s[s] + sdw;
        e = e > 0.f ? e : ALPHA * e;
        sm += expf(e - mx);
    }
    for (int o = 32; o; o >>= 1) sm += __shfl_xor(sm, o);
    float inv = (deg > 0) ? 1.f / sm : 0.f;

    for (int i = lane; i < deg; i += 64) {
        int s = csr[base + i];
        if ((unsigned)s >= (unsigned)N_) s = 0;
        float e = s2s[s] + sdw;
        e = e > 0.f ? e : ALPHA * e;
        att2[base + i] = expf(e - mx) * inv;
    }
}

// ---------------- layer-2 aggregate + log_softmax (f32 out) ----------------

__global__ __launch_bounds__(64) void k_agg2v(const int* __restrict__ rowptr, const int* __restrict__ csr,
                                              const float* __restrict__ att2, const float* __restrict__ Wh2,
                                              float* __restrict__ out) {
    int n = blockIdx.x;
    int base = rowptr[n], deg = rowptr[n + 1] - base;
    if (deg < 0) deg = 0;
    int lane = threadIdx.x;

    float acc = 0.f;
    for (int i = 0; i < deg; i++) {
        int s = csr[base + i];
        float a = att2[base + i];
        if ((unsigned)s >= (unsigned)N_) s = 0;
        if (lane < 40) acc += a * Wh2[(size_t)s * 40 + lane];
    }

    float v = (lane < 40) ? acc : -INFINITY;
    float mv = v;
    for (int o = 32; o; o >>= 1) mv = fmaxf(mv, __shfl_xor(mv, o));
    float ex = (lane < 40) ? expf(acc - mv) : 0.f;
    float se = ex;
    for (int o = 32; o; o >>= 1) se += __shfl_xor(se, o);
    if (lane < 40) out[(size_t)n * 40 + lane] = acc - mv - logf(se);
}

// ---------------- host ----------------

extern "C" void kernel_launch(void* const* d_in, const int* in_sizes, int n_in,
                              void* d_out, int out_size, void* d_ws, size_t ws_size,
                              hipStream_t stream) {
    const float* h   = (const float*)d_in[0];
    const int*   ei  = (const int*)d_in[1];
    const float* Whd = (const float*)d_in[2];
    const float* ah  = (const float*)d_in[3];
    const float* Wo  = (const float*)d_in[4];
    const float* ao  = (const float*)d_in[5];
    float* out = (float*)d_out;

    const int* src = ei;
    const int* dst = ei + E_;
    const int nchunks = (N_ + 1023) / 1024;

    char* ws = (char*)d_ws;
    size_t off = 0;
    auto alloc = [&](size_t bytes) -> char* {
        size_t a = (off + 255) & ~(size_t)255;
        off = a + bytes;
        return ws + a;
    };
    int* rowptr = (int*)alloc((size_t)(N_ + 1) * 4);
    int* cursor = (int*)alloc((size_t)N_ * 4);
    int* deg    = (int*)alloc((size_t)N_ * 4);
    int* part   = (int*)alloc((size_t)(nchunks + 1) * 4);
    int* csr    = (int*)alloc((size_t)E_ * 4);
    float* s1s  = (float*)alloc((size_t)N_ * 4 * 4);
    float* s1d  = (float*)alloc((size_t)N_ * 4 * 4);
    float* Wh2  = (float*)alloc((size_t)N_ * 40 * 4);
    float* s2s  = (float*)alloc((size_t)N_ * 4);
    float* s2d  = (float*)alloc((size_t)N_ * 4);
    float* att1 = (float*)alloc((size_t)E_ * 4 * 4);   // 25.6 MB
    float* att2 = (float*)alloc((size_t)E_ * 4);       // 6.4 MB
    float* Wh1  = (float*)alloc((size_t)N_ * 256 * 4); // 102.4 MB
    size_t base_need = off;
    size_t need_A = base_need + (size_t)N_ * 256 * 4 + 256;   // x f32
    size_t need_B = base_need + (size_t)N_ * 256 * 2 + 256;   // x bf16

    bool xf32;
    if (ws_size >= need_A) xf32 = true;
    else if (ws_size >= need_B) xf32 = false;
    else {
        k_sent<<<(int)((OUTEL + 255) / 256), 256, 0, stream>>>(out, OUTEL, -2.0f);
        return;
    }

    // CSR build
    k_zero<<<(N_ + 255) / 256, 256, 0, stream>>>(deg, N_);
    k_count<<<(E_ + 255) / 256, 256, 0, stream>>>(dst, deg);
    k_partial<<<nchunks, 256, 0, stream>>>(deg, part);
    k_scan_part<<<1, 64, 0, stream>>>(part, nchunks, rowptr);
    k_scan_final<<<nchunks, 256, 0, stream>>>(deg, part, rowptr, cursor);
    k_fill<<<(E_ + 255) / 256, 256, 0, stream>>>(src, dst, cursor, csr);

    // layer 1
    dim3 g1((N_ + 63) / 64, 4);
    k_gemm1<<<g1, 256, 0, stream>>>(h, Whd, Wh1);
    k_s1<<<N_, 256, 0, stream>>>(Wh1, ah, s1s, s1d);
    k_att1<<<N_, 256, 0, stream>>>(rowptr, csr, s1s, s1d, att1);

    if (xf32) {
        float* x = (float*)alloc((size_t)N_ * 256 * 4);
        k_agg1v<float><<<N_, 128, 0, stream>>>(rowptr, csr, att1, Wh1, x);
        k_gemm2<float><<<(N_ + 3) / 4, 256, 0, stream>>>(x, Wo, ao, Wh2, s2s, s2d);
    } else {
        unsigned short* x = (unsigned short*)alloc((size_t)N_ * 256 * 2);
        k_agg1v<unsigned short><<<N_, 128, 0, stream>>>(rowptr, csr, att1, Wh1, x);
        k_gemm2<unsigned short><<<(N_ + 3) / 4, 256, 0, stream>>>(x, Wo, ao, Wh2, s2s, s2d);
    }

    // layer 2
    k_att2<<<N_, 64, 0, stream>>>(rowptr, csr, s2s, s2d, att2);
    k_agg2v<<<N_, 64, 0, stream>>>(rowptr, csr, att2, Wh2, out);
}